// Round 7
// baseline (149.849 us; speedup 1.0000x reference)
//
#include <hip/hip_runtime.h>

#define BATCH   8192
#define SDIM    64
#define HDIM    128
#define NB      8      // batch rows per block (4 per thread, 2 row-groups)
#define PAD     12     // LDS row stride in floats (8 data + 4 pad, 16B-aligned)
#define UNFOLDS 4

typedef float f32x2 __attribute__((ext_vector_type(2)));
typedef float f32x4 __attribute__((ext_vector_type(4)));

// Packed fast reciprocal: bit-trick seed + 2 Newton steps (rel err ~6e-6).
// Replaces two 16-cyc v_rcp_f32 with ~12 cyc of full-rate packed VALU.
__device__ __forceinline__ f32x2 fastrcp2(f32x2 d) {
    f32x2 x;
    x.x = __int_as_float(0x7EF311C3 - __float_as_int(d.x));
    x.y = __int_as_float(0x7EF311C3 - __float_as_int(d.y));
    f32x2 two = {2.0f, 2.0f};
    f32x2 t = __builtin_elementwise_fma(-d, x, two);   // t = 2 - d*x
    x = x * t;
    t = __builtin_elementwise_fma(-d, x, two);
    x = x * t;
    return x;
}

// sigmoid pair: input z = -log2e*sigma*(x-mu); sigma(x) = 1/(1 + 2^z).
// Clamp z<=126 so e never becomes inf (seed needs finite d).
__device__ __forceinline__ f32x2 sigmoid2(f32x2 z) {
    z = __builtin_elementwise_min(z, (f32x2){126.0f, 126.0f});
    f32x2 e;
    e.x = __builtin_amdgcn_exp2f(z.x);
    e.y = __builtin_amdgcn_exp2f(z.y);
    f32x2 d = e + (f32x2){1.0f, 1.0f};
    return fastrcp2(d);
}

// acc over 4 rows packed in xv (f32x4), params P = {a, c, w, 0}
__device__ __forceinline__ void sig_acc(f32x4 P, f32x4 xv,
                                        f32x2& acc0, f32x2& acc1) {
    f32x2 av = {P.x, P.x}, cv = {P.y, P.y}, wv = {P.z, P.z};
    f32x2 r0 = sigmoid2(__builtin_elementwise_fma(xv.xy, av, cv));
    f32x2 r1 = sigmoid2(__builtin_elementwise_fma(xv.zw, av, cv));
    acc0 = __builtin_elementwise_fma(wv, r0, acc0);
    acc1 = __builtin_elementwise_fma(wv, r1, acc1);
}

// Pack {a, c, w, 0} per synapse: a = -log2e*sigma, c = -a*mu.
__global__ __launch_bounds__(256) void prep_kernel(
    const float* __restrict__ s_mu, const float* __restrict__ s_sig,
    const float* __restrict__ s_W,
    const float* __restrict__ h_mu, const float* __restrict__ h_sig,
    const float* __restrict__ h_W,
    f32x4* __restrict__ hpk, f32x4* __restrict__ spk)
{
    const float LOG2E = 1.4426950408889634f;
    int i = blockIdx.x * 256 + threadIdx.x;
    if (i < HDIM * HDIM) {
        float a = -LOG2E * h_sig[i];
        hpk[i] = (f32x4){a, -a * h_mu[i], h_W[i], 0.0f};
    }
    if (i < SDIM * HDIM) {
        float a = -LOG2E * s_sig[i];
        spk[i] = (f32x4){a, -a * s_mu[i], s_W[i], 0.0f};
    }
}

__global__ __launch_bounds__(256) void ltc_main(
    const float* __restrict__ input,    // [B,S]
    const float* __restrict__ hidden,   // [B,H]
    const f32x4* __restrict__ spk,      // [S,H] packed {a,c,w,0}
    const f32x4* __restrict__ hpk,      // [H,H] packed {a,c,w,0}
    const float* __restrict__ w_tau,    // [H]
    const float* __restrict__ w_A,      // [H]
    const float* __restrict__ elapsed,  // [1]
    float* __restrict__ out)            // [B,H]
{
    const int tid = threadIdx.x;
    const int h   = tid & (HDIM - 1);    // output feature
    const int g   = tid >> 7;            // row-group 0/1 -> rows 4g..4g+3
    const int b0  = blockIdx.x * NB;

    // Transposed, padded tiles: [pos][row-slot]; one ds_read_b128 = 4 rows.
    __shared__ float st [HDIM][PAD];     // 6 KB
    __shared__ float xin[SDIM][PAD];     // 3 KB

    for (int i = tid; i < NB * SDIM; i += 256) {
        int r = i >> 6, s = i & (SDIM - 1);
        xin[s][r] = input[(b0 + r) * SDIM + s];
    }
    for (int i = tid; i < NB * HDIM; i += 256) {
        int r = i >> 7, p = i & (HDIM - 1);
        st[p][r] = hidden[(b0 + r) * HDIM + p];
    }
    __syncthreads();

    const float dt = elapsed[0] * (1.0f / UNFOLDS);

#define LD4(arr, idx) (*(const f32x4*)&(arr)[idx][g * 4])

    // ---- sensory activation for this thread's 4 rows ----
    f32x2 sens0 = {0.0f, 0.0f}, sens1 = {0.0f, 0.0f};
    #pragma unroll 8
    for (int s = 0; s < SDIM; ++s) {
        f32x4 P = spk[s * HDIM + h];                 // one dwordx4
        f32x4 x = LD4(xin, s);                       // one ds_read_b128 (broadcast)
        sig_acc(P, x, sens0, sens1);
    }

    const float wT  = w_tau[h];
    const float wA  = w_A[h];
    const float dA  = dt * wA;
    const float dT1 = fmaf(dt, wT, 1.0f) + 1e-8f;   // 1 + dt*w_tau + EPS
    const f32x2 dAv  = {dA, dA};
    const f32x2 dtv  = {dt, dt};
    const f32x2 dT1v = {dT1, dT1};

    f32x4 ns;

    // ---- ODE unfolds ----
    for (int it = 0; it < UNFOLDS; ++it) {
        f32x2 acc0 = sens0, acc1 = sens1;

        #pragma unroll 8
        for (int p = 0; p < HDIM; ++p) {
            f32x4 P = hpk[p * HDIM + h];             // one dwordx4
            f32x4 x = LD4(st, p);                    // one ds_read_b128 (broadcast)
            sig_acc(P, x, acc0, acc1);
        }

        // new state = (st + dA*resp) / (1 + dt*w_tau + dt*resp + eps)
        f32x4 old = LD4(st, h);
        f32x2 n0 = __builtin_elementwise_fma(dAv, acc0, old.xy);
        f32x2 n1 = __builtin_elementwise_fma(dAv, acc1, old.zw);
        f32x2 d0 = __builtin_elementwise_fma(dtv, acc0, dT1v);
        f32x2 d1 = __builtin_elementwise_fma(dtv, acc1, dT1v);
        ns.x = n0.x * __builtin_amdgcn_rcpf(d0.x);
        ns.y = n0.y * __builtin_amdgcn_rcpf(d0.y);
        ns.z = n1.x * __builtin_amdgcn_rcpf(d1.x);
        ns.w = n1.y * __builtin_amdgcn_rcpf(d1.y);

        __syncthreads();                 // all reads of st done before overwrite
        *(f32x4*)&st[h][g * 4] = ns;
        __syncthreads();                 // writes visible before next unfold
    }

    // ---- output: this thread owns rows 4g..4g+3 at feature h ----
    out[(b0 + g * 4 + 0) * HDIM + h] = ns.x;
    out[(b0 + g * 4 + 1) * HDIM + h] = ns.y;
    out[(b0 + g * 4 + 2) * HDIM + h] = ns.z;
    out[(b0 + g * 4 + 3) * HDIM + h] = ns.w;
}

extern "C" void kernel_launch(void* const* d_in, const int* in_sizes, int n_in,
                              void* d_out, int out_size, void* d_ws, size_t ws_size,
                              hipStream_t stream) {
    const float* input   = (const float*)d_in[0];
    const float* hidden  = (const float*)d_in[1];
    const float* s_mu    = (const float*)d_in[2];
    const float* s_sig   = (const float*)d_in[3];
    const float* s_W     = (const float*)d_in[4];
    const float* h_mu    = (const float*)d_in[5];
    const float* h_sig   = (const float*)d_in[6];
    const float* h_W     = (const float*)d_in[7];
    const float* w_tau   = (const float*)d_in[8];
    const float* w_A     = (const float*)d_in[9];
    const float* elapsed = (const float*)d_in[10];
    float* out = (float*)d_out;

    // workspace: hpk [H*H] float4 (256 KB) then spk [S*H] float4 (128 KB)
    f32x4* hpk = (f32x4*)d_ws;
    f32x4* spk = hpk + HDIM * HDIM;

    prep_kernel<<<dim3((HDIM * HDIM + 255) / 256), dim3(256), 0, stream>>>(
        s_mu, s_sig, s_W, h_mu, h_sig, h_W, hpk, spk);

    ltc_main<<<dim3(BATCH / NB), dim3(256), 0, stream>>>(
        input, hidden, spk, hpk, w_tau, w_A, elapsed, out);
}

// Round 8
// 124.954 us; speedup vs baseline: 1.1992x; 1.1992x over previous
//
#include <hip/hip_runtime.h>

#define BATCH   8192
#define SDIM    64
#define HDIM    128
#define NB      8      // batch rows per block (4 per thread, 2 row-groups)
#define PAD     12     // LDS row stride in floats (8 data + 4 pad, 16B-aligned)
#define UNFOLDS 4

typedef float f32x2 __attribute__((ext_vector_type(2)));
typedef float f32x4 __attribute__((ext_vector_type(4)));

// acc over 4 rows packed in xv (f32x4), params P = {a, c, w, 0}.
// Pairwise-rcp: one rcp pair serves both sigmoid pairs:
//   r0 = 1/d0 = rcp(d0*d1)*d1,  r1 = rcp(d0*d1)*d0
// All non-trans ops stay v_pk_* (R7 lesson: scalarization doubles issue).
// Clamp z<=60: states reach ~1e4 so z can exceed 128 -> e=inf -> 0*inf=NaN.
__device__ __forceinline__ void sig_acc(f32x4 P, f32x4 xv,
                                        f32x2& acc0, f32x2& acc1) {
    f32x2 av = {P.x, P.x}, cv = {P.y, P.y}, wv = {P.z, P.z};
    const f32x2 one = {1.0f, 1.0f};
    const f32x2 cap = {60.0f, 60.0f};
    f32x2 z0 = __builtin_elementwise_fma(xv.xy, av, cv);
    f32x2 z1 = __builtin_elementwise_fma(xv.zw, av, cv);
    z0 = __builtin_elementwise_min(z0, cap);
    z1 = __builtin_elementwise_min(z1, cap);
    f32x2 e0, e1;
    e0.x = __builtin_amdgcn_exp2f(z0.x);
    e0.y = __builtin_amdgcn_exp2f(z0.y);
    e1.x = __builtin_amdgcn_exp2f(z1.x);
    e1.y = __builtin_amdgcn_exp2f(z1.y);
    f32x2 d0 = e0 + one;
    f32x2 d1 = e1 + one;
    f32x2 Pp = d0 * d1;
    f32x2 rP;
    rP.x = __builtin_amdgcn_rcpf(Pp.x);
    rP.y = __builtin_amdgcn_rcpf(Pp.y);
    f32x2 t = wv * rP;
    acc0 = __builtin_elementwise_fma(t, d1, acc0);   // w * 1/d0
    acc1 = __builtin_elementwise_fma(t, d0, acc1);   // w * 1/d1
}

// Pack {a, c, w, 0} per synapse: a = -log2e*sigma, c = -a*mu.
__global__ __launch_bounds__(256) void prep_kernel(
    const float* __restrict__ s_mu, const float* __restrict__ s_sig,
    const float* __restrict__ s_W,
    const float* __restrict__ h_mu, const float* __restrict__ h_sig,
    const float* __restrict__ h_W,
    f32x4* __restrict__ hpk, f32x4* __restrict__ spk)
{
    const float LOG2E = 1.4426950408889634f;
    int i = blockIdx.x * 256 + threadIdx.x;
    if (i < HDIM * HDIM) {
        float a = -LOG2E * h_sig[i];
        hpk[i] = (f32x4){a, -a * h_mu[i], h_W[i], 0.0f};
    }
    if (i < SDIM * HDIM) {
        float a = -LOG2E * s_sig[i];
        spk[i] = (f32x4){a, -a * s_mu[i], s_W[i], 0.0f};
    }
}

__global__ __launch_bounds__(256, 4) void ltc_main(
    const float* __restrict__ input,    // [B,S]
    const float* __restrict__ hidden,   // [B,H]
    const f32x4* __restrict__ spk,      // [S,H] packed {a,c,w,0}
    const f32x4* __restrict__ hpk,      // [H,H] packed {a,c,w,0}
    const float* __restrict__ w_tau,    // [H]
    const float* __restrict__ w_A,      // [H]
    const float* __restrict__ elapsed,  // [1]
    float* __restrict__ out)            // [B,H]
{
    const int tid = threadIdx.x;
    const int h   = tid & (HDIM - 1);    // output feature
    const int g   = tid >> 7;            // row-group 0/1 -> rows 4g..4g+3
    const int b0  = blockIdx.x * NB;

    // Transposed, padded tiles: [pos][row-slot]; one ds_read_b128 = 4 rows.
    __shared__ float st [HDIM][PAD];     // 6 KB
    __shared__ float xin[SDIM][PAD];     // 3 KB

    for (int i = tid; i < NB * SDIM; i += 256) {
        int r = i >> 6, s = i & (SDIM - 1);
        xin[s][r] = input[(b0 + r) * SDIM + s];
    }
    for (int i = tid; i < NB * HDIM; i += 256) {
        int r = i >> 7, p = i & (HDIM - 1);
        st[p][r] = hidden[(b0 + r) * HDIM + p];
    }
    __syncthreads();

    const float dt = elapsed[0] * (1.0f / UNFOLDS);

#define LD4(arr, idx) (*(const f32x4*)&(arr)[idx][g * 4])

    // ---- sensory activation for this thread's 4 rows ----
    f32x2 sens0 = {0.0f, 0.0f}, sens1 = {0.0f, 0.0f};
    #pragma unroll 8
    for (int s = 0; s < SDIM; ++s) {
        f32x4 P = spk[s * HDIM + h];                 // one dwordx4
        f32x4 x = LD4(xin, s);                       // one ds_read_b128 (broadcast)
        sig_acc(P, x, sens0, sens1);
    }

    const float wT  = w_tau[h];
    const float wA  = w_A[h];
    const float dA  = dt * wA;
    const float dT1 = fmaf(dt, wT, 1.0f) + 1e-8f;   // 1 + dt*w_tau + EPS
    const f32x2 dAv  = {dA, dA};
    const f32x2 dtv  = {dt, dt};
    const f32x2 dT1v = {dT1, dT1};

    f32x4 ns;

    // ---- ODE unfolds ----
    for (int it = 0; it < UNFOLDS; ++it) {
        f32x2 acc0 = sens0, acc1 = sens1;

        #pragma unroll 8
        for (int p = 0; p < HDIM; ++p) {
            f32x4 P = hpk[p * HDIM + h];             // one dwordx4
            f32x4 x = LD4(st, p);                    // one ds_read_b128 (broadcast)
            sig_acc(P, x, acc0, acc1);
        }

        // new state = (st + dA*resp) / (1 + dt*w_tau + dt*resp + eps)
        f32x4 old = LD4(st, h);
        f32x2 n0 = __builtin_elementwise_fma(dAv, acc0, old.xy);
        f32x2 n1 = __builtin_elementwise_fma(dAv, acc1, old.zw);
        f32x2 d0 = __builtin_elementwise_fma(dtv, acc0, dT1v);
        f32x2 d1 = __builtin_elementwise_fma(dtv, acc1, dT1v);
        ns.x = n0.x * __builtin_amdgcn_rcpf(d0.x);
        ns.y = n0.y * __builtin_amdgcn_rcpf(d0.y);
        ns.z = n1.x * __builtin_amdgcn_rcpf(d1.x);
        ns.w = n1.y * __builtin_amdgcn_rcpf(d1.y);

        __syncthreads();                 // all reads of st done before overwrite
        *(f32x4*)&st[h][g * 4] = ns;
        __syncthreads();                 // writes visible before next unfold
    }

    // ---- output: this thread owns rows 4g..4g+3 at feature h ----
    out[(b0 + g * 4 + 0) * HDIM + h] = ns.x;
    out[(b0 + g * 4 + 1) * HDIM + h] = ns.y;
    out[(b0 + g * 4 + 2) * HDIM + h] = ns.z;
    out[(b0 + g * 4 + 3) * HDIM + h] = ns.w;
}

extern "C" void kernel_launch(void* const* d_in, const int* in_sizes, int n_in,
                              void* d_out, int out_size, void* d_ws, size_t ws_size,
                              hipStream_t stream) {
    const float* input   = (const float*)d_in[0];
    const float* hidden  = (const float*)d_in[1];
    const float* s_mu    = (const float*)d_in[2];
    const float* s_sig   = (const float*)d_in[3];
    const float* s_W     = (const float*)d_in[4];
    const float* h_mu    = (const float*)d_in[5];
    const float* h_sig   = (const float*)d_in[6];
    const float* h_W     = (const float*)d_in[7];
    const float* w_tau   = (const float*)d_in[8];
    const float* w_A     = (const float*)d_in[9];
    const float* elapsed = (const float*)d_in[10];
    float* out = (float*)d_out;

    // workspace: hpk [H*H] float4 (256 KB) then spk [S*H] float4 (128 KB)
    f32x4* hpk = (f32x4*)d_ws;
    f32x4* spk = hpk + HDIM * HDIM;

    prep_kernel<<<dim3((HDIM * HDIM + 255) / 256), dim3(256), 0, stream>>>(
        s_mu, s_sig, s_W, h_mu, h_sig, h_W, hpk, spk);

    ltc_main<<<dim3(BATCH / NB), dim3(256), 0, stream>>>(
        input, hidden, spk, hpk, w_tau, w_A, elapsed, out);
}

// Round 9
// 124.504 us; speedup vs baseline: 1.2036x; 1.0036x over previous
//
#include <hip/hip_runtime.h>

#define BATCH   8192
#define SDIM    64
#define HDIM    128
#define NB      16     // batch rows per block (8 per thread, 2 row-groups)
#define NBP     20     // padded LDS row stride (16 data + 4 pad, keeps 16B align)
#define UNFOLDS 4

typedef float f32x2 __attribute__((ext_vector_type(2)));
typedef float f32x4 __attribute__((ext_vector_type(4)));

// acc over 4 rows packed in xv (f32x4), params P = {a, c, w, 0}.
// R4-proven form: all glue is v_pk_*, 4 exp + 4 rcp; rcp(inf)=0 handles
// saturated sigmoids cleanly with NO clamps (R8 lesson: clamps scalarize).
__device__ __forceinline__ void sig_acc(f32x4 P, f32x4 xv,
                                        f32x2& acc0, f32x2& acc1) {
    f32x2 av = {P.x, P.x}, cv = {P.y, P.y}, wv = {P.z, P.z};
    const f32x2 one = {1.0f, 1.0f};
    f32x2 z0 = __builtin_elementwise_fma(xv.xy, av, cv);
    f32x2 z1 = __builtin_elementwise_fma(xv.zw, av, cv);
    f32x2 e0, e1;
    e0.x = __builtin_amdgcn_exp2f(z0.x);
    e0.y = __builtin_amdgcn_exp2f(z0.y);
    e1.x = __builtin_amdgcn_exp2f(z1.x);
    e1.y = __builtin_amdgcn_exp2f(z1.y);
    f32x2 d0 = e0 + one;
    f32x2 d1 = e1 + one;
    f32x2 r0, r1;
    r0.x = __builtin_amdgcn_rcpf(d0.x);
    r0.y = __builtin_amdgcn_rcpf(d0.y);
    r1.x = __builtin_amdgcn_rcpf(d1.x);
    r1.y = __builtin_amdgcn_rcpf(d1.y);
    acc0 = __builtin_elementwise_fma(wv, r0, acc0);
    acc1 = __builtin_elementwise_fma(wv, r1, acc1);
}

// Pack {a, c, w, 0} per synapse: a = -log2e*sigma, c = -a*mu.
__global__ __launch_bounds__(256) void prep_kernel(
    const float* __restrict__ s_mu, const float* __restrict__ s_sig,
    const float* __restrict__ s_W,
    const float* __restrict__ h_mu, const float* __restrict__ h_sig,
    const float* __restrict__ h_W,
    f32x4* __restrict__ hpk, f32x4* __restrict__ spk)
{
    const float LOG2E = 1.4426950408889634f;
    int i = blockIdx.x * 256 + threadIdx.x;
    if (i < HDIM * HDIM) {
        float a = -LOG2E * h_sig[i];
        hpk[i] = (f32x4){a, -a * h_mu[i], h_W[i], 0.0f};
    }
    if (i < SDIM * HDIM) {
        float a = -LOG2E * s_sig[i];
        spk[i] = (f32x4){a, -a * s_mu[i], s_W[i], 0.0f};
    }
}

__global__ __launch_bounds__(256) void ltc_main(
    const float* __restrict__ input,    // [B,S]
    const float* __restrict__ hidden,   // [B,H]
    const f32x4* __restrict__ spk,      // [S,H] packed {a,c,w,0}
    const f32x4* __restrict__ hpk,      // [H,H] packed {a,c,w,0}
    const float* __restrict__ w_tau,    // [H]
    const float* __restrict__ w_A,      // [H]
    const float* __restrict__ elapsed,  // [1]
    float* __restrict__ out)            // [B,H]
{
    const int tid = threadIdx.x;
    const int h   = tid & (HDIM - 1);    // output feature
    const int g   = tid >> 7;            // row-group 0/1 -> rows 8g..8g+7
    const int b0  = blockIdx.x * NB;

    // Transposed, padded tiles: [pos][row-slot]; 2x ds_read_b128 = 8 rows.
    __shared__ float st [HDIM][NBP];     // 10 KB
    __shared__ float xin[SDIM][NBP];     // 5 KB

    for (int i = tid; i < NB * SDIM; i += 256) {
        int r = i >> 6, s = i & (SDIM - 1);
        xin[s][r] = input[(b0 + r) * SDIM + s];
    }
    for (int i = tid; i < NB * HDIM; i += 256) {
        int r = i >> 7, p = i & (HDIM - 1);
        st[p][r] = hidden[(b0 + r) * HDIM + p];
    }
    __syncthreads();

    const float dt = elapsed[0] * (1.0f / UNFOLDS);

    // two f32x4 row-chunks per thread: rows 8g..8g+3 and 8g+4..8g+7
#define LD4A(arr, idx) (*(const f32x4*)&(arr)[idx][g * 8])
#define LD4B(arr, idx) (*(const f32x4*)&(arr)[idx][g * 8 + 4])

    // ---- sensory activation for this thread's 8 rows ----
    f32x2 sA0 = {0.0f, 0.0f}, sA1 = {0.0f, 0.0f};
    f32x2 sB0 = {0.0f, 0.0f}, sB1 = {0.0f, 0.0f};
    #pragma unroll 4
    for (int s = 0; s < SDIM; ++s) {
        f32x4 P  = spk[s * HDIM + h];                // one dwordx4 (L2)
        f32x4 xa = LD4A(xin, s);                     // ds_read_b128 (broadcast)
        f32x4 xb = LD4B(xin, s);
        sig_acc(P, xa, sA0, sA1);
        sig_acc(P, xb, sB0, sB1);
    }

    const float wT  = w_tau[h];
    const float wA  = w_A[h];
    const float dA  = dt * wA;
    const float dT1 = fmaf(dt, wT, 1.0f) + 1e-8f;   // 1 + dt*w_tau + EPS
    const f32x2 dAv  = {dA, dA};
    const f32x2 dtv  = {dt, dt};
    const f32x2 dT1v = {dT1, dT1};

    f32x4 nsA, nsB;

    // ---- ODE unfolds ----
    for (int it = 0; it < UNFOLDS; ++it) {
        f32x2 aA0 = sA0, aA1 = sA1, aB0 = sB0, aB1 = sB1;

        #pragma unroll 4
        for (int p = 0; p < HDIM; ++p) {
            f32x4 P  = hpk[p * HDIM + h];            // one dwordx4 (L2)
            f32x4 xa = LD4A(st, p);                  // ds_read_b128 (broadcast)
            f32x4 xb = LD4B(st, p);
            sig_acc(P, xa, aA0, aA1);
            sig_acc(P, xb, aB0, aB1);
        }

        // new state = (st + dA*resp) / (1 + dt*w_tau + dt*resp + eps)
        f32x4 oldA = LD4A(st, h);
        f32x4 oldB = LD4B(st, h);
        f32x2 nA0 = __builtin_elementwise_fma(dAv, aA0, oldA.xy);
        f32x2 nA1 = __builtin_elementwise_fma(dAv, aA1, oldA.zw);
        f32x2 nB0 = __builtin_elementwise_fma(dAv, aB0, oldB.xy);
        f32x2 nB1 = __builtin_elementwise_fma(dAv, aB1, oldB.zw);
        f32x2 dA0 = __builtin_elementwise_fma(dtv, aA0, dT1v);
        f32x2 dA1 = __builtin_elementwise_fma(dtv, aA1, dT1v);
        f32x2 dB0 = __builtin_elementwise_fma(dtv, aB0, dT1v);
        f32x2 dB1 = __builtin_elementwise_fma(dtv, aB1, dT1v);
        nsA.x = nA0.x * __builtin_amdgcn_rcpf(dA0.x);
        nsA.y = nA0.y * __builtin_amdgcn_rcpf(dA0.y);
        nsA.z = nA1.x * __builtin_amdgcn_rcpf(dA1.x);
        nsA.w = nA1.y * __builtin_amdgcn_rcpf(dA1.y);
        nsB.x = nB0.x * __builtin_amdgcn_rcpf(dB0.x);
        nsB.y = nB0.y * __builtin_amdgcn_rcpf(dB0.y);
        nsB.z = nB1.x * __builtin_amdgcn_rcpf(dB1.x);
        nsB.w = nB1.y * __builtin_amdgcn_rcpf(dB1.y);

        __syncthreads();                 // all reads of st done before overwrite
        *(f32x4*)&st[h][g * 8]     = nsA;
        *(f32x4*)&st[h][g * 8 + 4] = nsB;
        __syncthreads();                 // writes visible before next unfold
    }

    // ---- output: this thread owns rows 8g..8g+7 at feature h ----
    out[(b0 + g * 8 + 0) * HDIM + h] = nsA.x;
    out[(b0 + g * 8 + 1) * HDIM + h] = nsA.y;
    out[(b0 + g * 8 + 2) * HDIM + h] = nsA.z;
    out[(b0 + g * 8 + 3) * HDIM + h] = nsA.w;
    out[(b0 + g * 8 + 4) * HDIM + h] = nsB.x;
    out[(b0 + g * 8 + 5) * HDIM + h] = nsB.y;
    out[(b0 + g * 8 + 6) * HDIM + h] = nsB.z;
    out[(b0 + g * 8 + 7) * HDIM + h] = nsB.w;
}

extern "C" void kernel_launch(void* const* d_in, const int* in_sizes, int n_in,
                              void* d_out, int out_size, void* d_ws, size_t ws_size,
                              hipStream_t stream) {
    const float* input   = (const float*)d_in[0];
    const float* hidden  = (const float*)d_in[1];
    const float* s_mu    = (const float*)d_in[2];
    const float* s_sig   = (const float*)d_in[3];
    const float* s_W     = (const float*)d_in[4];
    const float* h_mu    = (const float*)d_in[5];
    const float* h_sig   = (const float*)d_in[6];
    const float* h_W     = (const float*)d_in[7];
    const float* w_tau   = (const float*)d_in[8];
    const float* w_A     = (const float*)d_in[9];
    const float* elapsed = (const float*)d_in[10];
    float* out = (float*)d_out;

    // workspace: hpk [H*H] float4 (256 KB) then spk [S*H] float4 (128 KB)
    f32x4* hpk = (f32x4*)d_ws;
    f32x4* spk = hpk + HDIM * HDIM;

    prep_kernel<<<dim3((HDIM * HDIM + 255) / 256), dim3(256), 0, stream>>>(
        s_mu, s_sig, s_W, h_mu, h_sig, h_W, hpk, spk);

    ltc_main<<<dim3(BATCH / NB), dim3(256), 0, stream>>>(
        input, hidden, spk, hpk, w_tau, w_A, elapsed, out);
}

// Round 10
// 117.350 us; speedup vs baseline: 1.2769x; 1.0610x over previous
//
#include <hip/hip_runtime.h>

#define BATCH   8192
#define SDIM    64
#define HDIM    128
#define NB      8      // batch rows per block (4 per thread, 2 row-groups)
#define UNFOLDS 4

typedef float f32x2 __attribute__((ext_vector_type(2)));
typedef float f32x4 __attribute__((ext_vector_type(4)));

__device__ __forceinline__ f32x2 sigmoid2(f32x2 z) {
    // z = -log2e * sig * (x - mu); returns 1/(1+exp2(z))
    // rcp(inf)=0 handles saturation exactly; no clamps (they scalarize).
    f32x2 e;
    e.x = __builtin_amdgcn_exp2f(z.x);
    e.y = __builtin_amdgcn_exp2f(z.y);
    f32x2 d = e + (f32x2){1.0f, 1.0f};
    f32x2 r;
    r.x = __builtin_amdgcn_rcpf(d.x);
    r.y = __builtin_amdgcn_rcpf(d.y);
    return r;
}

// Pack {a, c, w, 0} per synapse so the hot loop does ONE dwordx4 load
// instead of 3 scalar loads + 2 muls.  a = -log2e*sigma, c = -a*mu.
__global__ __launch_bounds__(256) void prep_kernel(
    const float* __restrict__ s_mu, const float* __restrict__ s_sig,
    const float* __restrict__ s_W,
    const float* __restrict__ h_mu, const float* __restrict__ h_sig,
    const float* __restrict__ h_W,
    f32x4* __restrict__ hpk, f32x4* __restrict__ spk)
{
    const float LOG2E = 1.4426950408889634f;
    int i = blockIdx.x * 256 + threadIdx.x;
    if (i < HDIM * HDIM) {
        float a = -LOG2E * h_sig[i];
        hpk[i] = (f32x4){a, -a * h_mu[i], h_W[i], 0.0f};
    }
    if (i < SDIM * HDIM) {
        float a = -LOG2E * s_sig[i];
        spk[i] = (f32x4){a, -a * s_mu[i], s_W[i], 0.0f};
    }
}

__global__ __launch_bounds__(256) void ltc_main(
    const float* __restrict__ input,    // [B,S]
    const float* __restrict__ hidden,   // [B,H]
    const f32x4* __restrict__ spk,      // [S,H] packed {a,c,w,0}
    const f32x4* __restrict__ hpk,      // [H,H] packed {a,c,w,0}
    const float* __restrict__ w_tau,    // [H]
    const float* __restrict__ w_A,      // [H]
    const float* __restrict__ elapsed,  // [1]
    float* __restrict__ out)            // [B,H]
{
    const int tid = threadIdx.x;
    const int h   = tid & (HDIM - 1);    // output feature
    const int g   = tid >> 7;            // row-group 0/1 -> rows 4g..4g+3
    const int b0  = blockIdx.x * NB;

    // TRANSPOSED tiles: [pos][row] so one ds_read_b128 = 4 rows (broadcast).
    __shared__ float st [HDIM][NB];      // 4 KB
    __shared__ float xin[SDIM][NB];      // 2 KB

    for (int i = tid; i < NB * SDIM; i += 256) {
        int r = i >> 6, s = i & (SDIM - 1);
        xin[s][r] = input[(b0 + r) * SDIM + s];
    }
    for (int i = tid; i < NB * HDIM; i += 256) {
        int r = i >> 7, p = i & (HDIM - 1);
        st[p][r] = hidden[(b0 + r) * HDIM + p];
    }
    __syncthreads();

    const float dt = elapsed[0] * (1.0f / UNFOLDS);

    // ---- sensory activation for this thread's 4 rows ----
    f32x2 sens0 = {0.0f, 0.0f}, sens1 = {0.0f, 0.0f};
    #pragma unroll 8
    for (int s = 0; s < SDIM; ++s) {
        f32x4 P = spk[s * HDIM + h];                 // one dwordx4
        f32x4 x = *(const f32x4*)&xin[s][g * 4];     // one ds_read_b128 (broadcast)
        f32x2 av = {P.x, P.x}, cv = {P.y, P.y}, wv = {P.z, P.z};
        f32x2 r0 = sigmoid2(__builtin_elementwise_fma(x.xy, av, cv));
        f32x2 r1 = sigmoid2(__builtin_elementwise_fma(x.zw, av, cv));
        sens0 = __builtin_elementwise_fma(wv, r0, sens0);
        sens1 = __builtin_elementwise_fma(wv, r1, sens1);
    }

    const float wT  = w_tau[h];
    const float wA  = w_A[h];
    const float dA  = dt * wA;
    const float dT1 = fmaf(dt, wT, 1.0f) + 1e-8f;   // 1 + dt*w_tau + EPS
    const f32x2 dAv  = {dA, dA};
    const f32x2 dtv  = {dt, dt};
    const f32x2 dT1v = {dT1, dT1};

    f32x4 ns;

    // ---- ODE unfolds ----
    for (int it = 0; it < UNFOLDS; ++it) {
        f32x2 acc0 = sens0, acc1 = sens1;

        #pragma unroll 8
        for (int p = 0; p < HDIM; ++p) {
            f32x4 P = hpk[p * HDIM + h];             // one dwordx4
            f32x4 x = *(const f32x4*)&st[p][g * 4];  // one ds_read_b128 (broadcast)
            f32x2 av = {P.x, P.x}, cv = {P.y, P.y}, wv = {P.z, P.z};
            f32x2 r0 = sigmoid2(__builtin_elementwise_fma(x.xy, av, cv));
            f32x2 r1 = sigmoid2(__builtin_elementwise_fma(x.zw, av, cv));
            acc0 = __builtin_elementwise_fma(wv, r0, acc0);
            acc1 = __builtin_elementwise_fma(wv, r1, acc1);
        }

        // new state = (st + dA*resp) / (1 + dt*w_tau + dt*resp + eps)
        f32x4 old = *(const f32x4*)&st[h][g * 4];
        f32x2 n0 = __builtin_elementwise_fma(dAv, acc0, old.xy);
        f32x2 n1 = __builtin_elementwise_fma(dAv, acc1, old.zw);
        f32x2 d0 = __builtin_elementwise_fma(dtv, acc0, dT1v);
        f32x2 d1 = __builtin_elementwise_fma(dtv, acc1, dT1v);
        ns.x = n0.x * __builtin_amdgcn_rcpf(d0.x);
        ns.y = n0.y * __builtin_amdgcn_rcpf(d0.y);
        ns.z = n1.x * __builtin_amdgcn_rcpf(d1.x);
        ns.w = n1.y * __builtin_amdgcn_rcpf(d1.y);

        __syncthreads();                 // all reads of st done before overwrite
        *(f32x4*)&st[h][g * 4] = ns;
        __syncthreads();                 // writes visible before next unfold
    }

    // ---- output: this thread owns rows 4g..4g+3 at feature h ----
    out[(b0 + g * 4 + 0) * HDIM + h] = ns.x;
    out[(b0 + g * 4 + 1) * HDIM + h] = ns.y;
    out[(b0 + g * 4 + 2) * HDIM + h] = ns.z;
    out[(b0 + g * 4 + 3) * HDIM + h] = ns.w;
}

extern "C" void kernel_launch(void* const* d_in, const int* in_sizes, int n_in,
                              void* d_out, int out_size, void* d_ws, size_t ws_size,
                              hipStream_t stream) {
    const float* input   = (const float*)d_in[0];
    const float* hidden  = (const float*)d_in[1];
    const float* s_mu    = (const float*)d_in[2];
    const float* s_sig   = (const float*)d_in[3];
    const float* s_W     = (const float*)d_in[4];
    const float* h_mu    = (const float*)d_in[5];
    const float* h_sig   = (const float*)d_in[6];
    const float* h_W     = (const float*)d_in[7];
    const float* w_tau   = (const float*)d_in[8];
    const float* w_A     = (const float*)d_in[9];
    const float* elapsed = (const float*)d_in[10];
    float* out = (float*)d_out;

    // workspace: hpk [H*H] float4 (256 KB) then spk [S*H] float4 (128 KB)
    f32x4* hpk = (f32x4*)d_ws;
    f32x4* spk = hpk + HDIM * HDIM;

    prep_kernel<<<dim3((HDIM * HDIM + 255) / 256), dim3(256), 0, stream>>>(
        s_mu, s_sig, s_W, h_mu, h_sig, h_W, hpk, spk);

    ltc_main<<<dim3(BATCH / NB), dim3(256), 0, stream>>>(
        input, hidden, spk, hpk, w_tau, w_A, elapsed, out);
}